// Round 1
// baseline (105.246 us; speedup 1.0000x reference)
//
#include <hip/hip_runtime.h>

// PSANet 'distribute':
// out[n, h*W + w, i, j] = x[n, (i-h+H-1)*(2W-1) + (j-w+W-1), h, w]
// N=2, H=W=64, HM=WM=127.
//
// Pure permutation. Block = one (n, h, i) triple; di = i-h+63 fixed.
// Input band: element (dj, w) with j = dj+w-63 in [0,64) -> lds[w][j].
// Load: per-row (w-contiguous) predicated dword loads, coalesced.
// Store: float4 from lds[w][j], contiguous in j, coalesced.

#define PSA_H 64
#define PSA_W 64
#define PSA_HM 127
#define PSA_WM 127
#define PSA_HW (PSA_H * PSA_W)      // 4096
#define PSA_CHW (PSA_HM * PSA_WM)   // 16129

__global__ __launch_bounds__(256) void psa_distribute_kernel(
    const float* __restrict__ in, float* __restrict__ out) {
    __shared__ float lds[PSA_W * PSA_W];  // lds[w][j], 16 KiB

    const int b = blockIdx.x;
    const int n = b >> 12;          // grid = N * 64 * 64
    const int r = b & 4095;
    const int u = r >> 6;           // diagonal group: i = (h+u) & 63
    const int h = r & 63;
    const int i = (h + u) & 63;
    const int di = i - h + (PSA_H - 1);   // in [0, 126]

    // element offset of (dj=0, w=0) in this block's slab
    const size_t in_base =
        ((size_t)n * PSA_CHW + (size_t)di * PSA_WM) * (size_t)PSA_HW
        + (size_t)h * PSA_W;

    const int lane = threadIdx.x & 63;   // = w
    const int wv   = threadIdx.x >> 6;   // wave id 0..3

    // Load phase: each wave takes rows dj = wv, wv+4, ... (127 rows total).
    // lane = w; valid iff j = dj + w - 63 in [0,64).
    for (int dj = wv; dj < PSA_WM; dj += 4) {
        const int j = dj + lane - (PSA_W - 1);
        if ((unsigned)j < (unsigned)PSA_W) {
            lds[lane * PSA_W + j] = in[in_base + (size_t)dj * PSA_HW + lane];
        }
    }
    __syncthreads();

    // Store phase: out flat = (n*4096 + h*64 + w)*4096 + i*64 + j
    const size_t out_base =
        ((size_t)(n * PSA_HW) + (size_t)h * PSA_W) * (size_t)PSA_HW
        + (size_t)i * PSA_W;

    const float4* lds4 = (const float4*)lds;
    float4* out4 = (float4*)(out + out_base);  // aligned: out_base % 64 == 0
    const int t = threadIdx.x;
#pragma unroll
    for (int k = 0; k < 4; ++k) {
        const int id = k * 256 + t;      // float4 id, 0..1023
        const int w  = id >> 4;          // 16 float4 per w-row
        const int j4 = id & 15;
        out4[w * (PSA_HW / 4) + j4] = lds4[id];
    }
}

extern "C" void kernel_launch(void* const* d_in, const int* in_sizes, int n_in,
                              void* d_out, int out_size, void* d_ws, size_t ws_size,
                              hipStream_t stream) {
    const float* x = (const float*)d_in[0];
    float* out = (float*)d_out;
    const int nblocks = 2 * PSA_H * PSA_H;  // 8192
    psa_distribute_kernel<<<nblocks, 256, 0, stream>>>(x, out);
}

// Round 2
// 73.226 us; speedup vs baseline: 1.4373x; 1.4373x over previous
//
#include <hip/hip_runtime.h>

// PSANet 'distribute':
// out[n, h*W + w, i, j] = x[n, (i-h+H-1)*(2W-1) + (j-w+W-1), h, w]
// N=2, H=W=64, HM=WM=127.
//
// Pure permutation, output-driven. Block = one (n, h, i); di = i-h+63 fixed.
// Input band: element (dj, w) used iff j = dj+w-63 in [0,64); -> lds[w][j].
// Load: float4 per lane, 4 band rows per wave-instruction, predicated to the
//       valid float4 range (fetch = same lines as scalar version).
// LDS scatter: 4 predicated ds_write_b32, addr = (4wl+e)*65 + dj - 63
//       -> banks (4wl+e+dj+1)%32: 64 lanes cover 32 banks 2x = free.
// Store: float4 LDS reads + dense float4 global stores (unchanged).

#define PSA_H 64
#define PSA_W 64
#define PSA_HM 127
#define PSA_WM 127
#define PSA_HW (PSA_H * PSA_W)      // 4096
#define PSA_CHW (PSA_HM * PSA_WM)   // 16129

__global__ __launch_bounds__(256) void psa_distribute_kernel(
    const float* __restrict__ in, float* __restrict__ out) {
    __shared__ float lds[PSA_W * PSA_W];  // lds[w][j], 16 KiB

    const int b = blockIdx.x;
    const int n = b >> 12;            // grid = N * 64 * 64
    const int h = (b >> 6) & 63;
    const int i = b & 63;
    const int di = i - h + (PSA_H - 1);   // in [0, 126]

    // element offset of (dj=0, w=0) in this block's slab
    const size_t in_base =
        ((size_t)n * PSA_CHW + (size_t)di * PSA_WM) * (size_t)PSA_HW
        + (size_t)h * PSA_W;

    const int lane = threadIdx.x & 63;
    const int wv   = threadIdx.x >> 6;   // wave id 0..3
    const int rr   = lane >> 4;          // row within 4-row group
    const int wl   = lane & 15;          // float4 column
    const int wbase = wl << 2;           // w of element 0 of this lane's float4

    // 127 rows in 32 groups of 4; wave wv takes groups g = wv, wv+4, ...
#pragma unroll
    for (int g4 = 0; g4 < 8; ++g4) {
        const int g  = g4 * 4 + wv;
        const int dj = g * 4 + rr;                 // 0..127 (127 masked)
        // valid w range: [max(0,63-dj), min(63,126-dj)]
        const bool active = (dj < PSA_WM) &&
                            (wbase + 3 >= PSA_W - 1 - dj) &&
                            (wbase <= 2 * (PSA_W - 1) - dj);
        if (active) {
            const float4 v =
                *(const float4*)(in + in_base + (size_t)dj * PSA_HW + wbase);
            const int jb = dj + wbase - (PSA_W - 1);
#pragma unroll
            for (int e = 0; e < 4; ++e) {
                const int j = jb + e;
                if ((unsigned)j < (unsigned)PSA_W) {
                    lds[(wbase + e) * PSA_W + j] = ((const float*)&v)[e];
                }
            }
        }
    }
    __syncthreads();

    // Store phase: out flat = (n*4096 + h*64 + w)*4096 + i*64 + j
    const size_t out_base =
        ((size_t)(n * PSA_HW) + (size_t)h * PSA_W) * (size_t)PSA_HW
        + (size_t)i * PSA_W;

    const float4* lds4 = (const float4*)lds;
    float4* out4 = (float4*)(out + out_base);  // out_base % 64 == 0
    const int t = threadIdx.x;
#pragma unroll
    for (int k = 0; k < 4; ++k) {
        const int id = k * 256 + t;      // float4 id, 0..1023
        const int w  = id >> 4;          // 16 float4 per w-row
        const int j4 = id & 15;
        out4[w * (PSA_HW / 4) + j4] = lds4[id];
    }
}

extern "C" void kernel_launch(void* const* d_in, const int* in_sizes, int n_in,
                              void* d_out, int out_size, void* d_ws, size_t ws_size,
                              hipStream_t stream) {
    const float* x = (const float*)d_in[0];
    float* out = (float*)d_out;
    const int nblocks = 2 * PSA_H * PSA_H;  // 8192
    psa_distribute_kernel<<<nblocks, 256, 0, stream>>>(x, out);
}

// Round 3
// 72.138 us; speedup vs baseline: 1.4590x; 1.0151x over previous
//
#include <hip/hip_runtime.h>

// PSANet 'distribute':
// out[n, h*W + w, i, j] = x[n, (i-h+H-1)*(2W-1) + (j-w+W-1), h, w]
// N=2, H=W=64, HM=WM=127.
//
// Pure permutation, output-driven. Block = one (n, h, i); di = i-h+63 fixed.
// Input band: element (dj, w) used iff j = dj+w-63 in [0,64); -> lds[w][j].
// Load: float4 per lane, 4 band rows per wave-instruction, predicated to the
//       valid float4 range (line-optimal fetch).
// Store: float4 LDS reads + dense float4 global stores.
// Block ordering: 8x8 (h,i) tiles -> concurrent blocks get read-side
//       h-adjacency (dense channel-row runs) AND write-side i-adjacency
//       (2KB dense output runs) for DRAM page locality.

#define PSA_H 64
#define PSA_W 64
#define PSA_HM 127
#define PSA_WM 127
#define PSA_HW (PSA_H * PSA_W)      // 4096
#define PSA_CHW (PSA_HM * PSA_WM)   // 16129

__global__ __launch_bounds__(256) void psa_distribute_kernel(
    const float* __restrict__ in, float* __restrict__ out) {
    __shared__ float lds[PSA_W * PSA_W];  // lds[w][j], 16 KiB

    const int b = blockIdx.x;
    const int n = b >> 12;            // grid = N * 64 * 64
    // 8x8 tile decode: 64 consecutive blocks = one 8h x 8i tile
    const int local = b & 63;
    const int t     = (b >> 6) & 63;
    const int h = ((t >> 3) << 3) + ((local >> 3) & 7);
    const int i = ((t & 7) << 3) + (local & 7);
    const int di = i - h + (PSA_H - 1);   // in [0, 126]

    // element offset of (dj=0, w=0) in this block's slab
    const size_t in_base =
        ((size_t)n * PSA_CHW + (size_t)di * PSA_WM) * (size_t)PSA_HW
        + (size_t)h * PSA_W;

    const int lane = threadIdx.x & 63;
    const int wv   = threadIdx.x >> 6;   // wave id 0..3
    const int rr   = lane >> 4;          // row within 4-row group
    const int wl   = lane & 15;          // float4 column
    const int wbase = wl << 2;           // w of element 0 of this lane's float4

    // 127 rows in 32 groups of 4; wave wv takes groups g = wv, wv+4, ...
#pragma unroll
    for (int g4 = 0; g4 < 8; ++g4) {
        const int g  = g4 * 4 + wv;
        const int dj = g * 4 + rr;                 // 0..127 (127 masked)
        // valid w range: [max(0,63-dj), min(63,126-dj)]
        const bool active = (dj < PSA_WM) &&
                            (wbase + 3 >= PSA_W - 1 - dj) &&
                            (wbase <= 2 * (PSA_W - 1) - dj);
        if (active) {
            const float4 v =
                *(const float4*)(in + in_base + (size_t)dj * PSA_HW + wbase);
            const int jb = dj + wbase - (PSA_W - 1);
#pragma unroll
            for (int e = 0; e < 4; ++e) {
                const int j = jb + e;
                if ((unsigned)j < (unsigned)PSA_W) {
                    lds[(wbase + e) * PSA_W + j] = ((const float*)&v)[e];
                }
            }
        }
    }
    __syncthreads();

    // Store phase: out flat = (n*4096 + h*64 + w)*4096 + i*64 + j
    const size_t out_base =
        ((size_t)(n * PSA_HW) + (size_t)h * PSA_W) * (size_t)PSA_HW
        + (size_t)i * PSA_W;

    const float4* lds4 = (const float4*)lds;
    float4* out4 = (float4*)(out + out_base);  // out_base % 64 == 0
    const int tt = threadIdx.x;
#pragma unroll
    for (int k = 0; k < 4; ++k) {
        const int id = k * 256 + tt;     // float4 id, 0..1023
        const int w  = id >> 4;          // 16 float4 per w-row
        const int j4 = id & 15;
        out4[w * (PSA_HW / 4) + j4] = lds4[id];
    }
}

extern "C" void kernel_launch(void* const* d_in, const int* in_sizes, int n_in,
                              void* d_out, int out_size, void* d_ws, size_t ws_size,
                              hipStream_t stream) {
    const float* x = (const float*)d_in[0];
    float* out = (float*)d_out;
    const int nblocks = 2 * PSA_H * PSA_H;  // 8192
    psa_distribute_kernel<<<nblocks, 256, 0, stream>>>(x, out);
}

// Round 4
// 70.402 us; speedup vs baseline: 1.4949x; 1.0247x over previous
//
#include <hip/hip_runtime.h>

// PSANet 'distribute':
// out[n, h*W + w, i, j] = x[n, (i-h+H-1)*(2W-1) + (j-w+W-1), h, w]
// N=2, H=W=64, HM=WM=127.
//
// Pure permutation, output-driven. Block = one (n, h, i); di = i-h+63 fixed.
// Load: float4 per lane, predicated to the valid band (line-optimal fetch).
// Store: float4 LDS reads + dense float4 global stores.
// Block ordering: XCD-aware (T1). Dispatch round-robins blockIdx across the
// 8 XCDs, so swz id s = (bid&7)*1024 + bid>>3 gives each XCD a CONTIGUOUS
// 1024-id range; s decodes as 4x4 tiles of 16x16 (h,i). The ~256 resident
// blocks per XCD then share one L2: 16 adjacent i -> 4KB-dense write runs
// per plane, ~8 adjacent h at shared di -> ~2KB-dense read windows.

#define PSA_H 64
#define PSA_W 64
#define PSA_HM 127
#define PSA_WM 127
#define PSA_HW (PSA_H * PSA_W)      // 4096
#define PSA_CHW (PSA_HM * PSA_WM)   // 16129

__global__ __launch_bounds__(256) void psa_distribute_kernel(
    const float* __restrict__ in, float* __restrict__ out) {
    __shared__ float lds[PSA_W * PSA_W];  // lds[w][j], 16 KiB

    const int b = blockIdx.x;
    // XCD-contiguous swizzle: grid 8192, 8 XCDs, round-robin dispatch
    const int xcd = b & 7;
    const int k   = b >> 3;              // 0..1023
    const int s   = (xcd << 10) + k;     // swizzled linear id
    const int n   = s >> 12;
    const int r   = s & 4095;            // (h,i) space
    const int t   = r >> 8;              // 16 tiles (4x4) of 16x16
    const int q   = r & 255;
    const int h   = ((t >> 2) << 4) + (q >> 4);
    const int i   = ((t & 3) << 4) + (q & 15);
    const int di  = i - h + (PSA_H - 1);   // in [0, 126]

    // element offset of (dj=0, w=0) in this block's slab
    const size_t in_base =
        ((size_t)n * PSA_CHW + (size_t)di * PSA_WM) * (size_t)PSA_HW
        + (size_t)h * PSA_W;

    const int lane = threadIdx.x & 63;
    const int wv   = threadIdx.x >> 6;   // wave id 0..3
    const int rr   = lane >> 4;          // row within 4-row group
    const int wl   = lane & 15;          // float4 column
    const int wbase = wl << 2;           // w of element 0 of this lane's float4

    // 127 rows in 32 groups of 4; wave wv takes groups g = wv, wv+4, ...
#pragma unroll
    for (int g4 = 0; g4 < 8; ++g4) {
        const int g  = g4 * 4 + wv;
        const int dj = g * 4 + rr;                 // 0..127 (127 masked)
        // valid w range: [max(0,63-dj), min(63,126-dj)]
        const bool active = (dj < PSA_WM) &&
                            (wbase + 3 >= PSA_W - 1 - dj) &&
                            (wbase <= 2 * (PSA_W - 1) - dj);
        if (active) {
            const float4 v =
                *(const float4*)(in + in_base + (size_t)dj * PSA_HW + wbase);
            const int jb = dj + wbase - (PSA_W - 1);
#pragma unroll
            for (int e = 0; e < 4; ++e) {
                const int j = jb + e;
                if ((unsigned)j < (unsigned)PSA_W) {
                    lds[(wbase + e) * PSA_W + j] = ((const float*)&v)[e];
                }
            }
        }
    }
    __syncthreads();

    // Store phase: out flat = (n*4096 + h*64 + w)*4096 + i*64 + j
    const size_t out_base =
        ((size_t)(n * PSA_HW) + (size_t)h * PSA_W) * (size_t)PSA_HW
        + (size_t)i * PSA_W;

    const float4* lds4 = (const float4*)lds;
    float4* out4 = (float4*)(out + out_base);  // out_base % 64 == 0
    const int tt = threadIdx.x;
#pragma unroll
    for (int kk = 0; kk < 4; ++kk) {
        const int id = kk * 256 + tt;    // float4 id, 0..1023
        const int w  = id >> 4;          // 16 float4 per w-row
        const int j4 = id & 15;
        out4[w * (PSA_HW / 4) + j4] = lds4[id];
    }
}

extern "C" void kernel_launch(void* const* d_in, const int* in_sizes, int n_in,
                              void* d_out, int out_size, void* d_ws, size_t ws_size,
                              hipStream_t stream) {
    const float* x = (const float*)d_in[0];
    float* out = (float*)d_out;
    const int nblocks = 2 * PSA_H * PSA_H;  // 8192
    psa_distribute_kernel<<<nblocks, 256, 0, stream>>>(x, out);
}